// Round 6
// baseline (659.529 us; speedup 1.0000x reference)
//
#include <hip/hip_runtime.h>
#include <stdint.h>

// JointSlotFusion on MI355X (gfx950).
// ws layout (bytes):
//   kbuf   bf16[128][2048][64]   @ 0          (33,554,432)   token-major
//   vT     bf16[128][64][2048]   @ 33,554,432 (33,554,432)   d-major (transposed)
//   wconv  bf16[2][64][256]      @ 67,108,864 (65,536)
//   wkv    bf16[2][64][64]       @ 67,174,400 (16,384)
//   slotbuf f32[128][8][64]      @ 67,190,784 (262,144)  slots_1 (written by kA_iter it=2)
//   updf   f32[2][128][8][8][64] @ 67,452,928 (4,194,304) chunk partials, gen ping-pong
//   colf   f32[2][128][8][8]     @ 71,647,232 (65,536)    chunk colsums, gen ping-pong
//   (total 71,712,768 <= previous footprint 71,843,840)

typedef __bf16 bf16;
typedef __bf16 bf16x8 __attribute__((ext_vector_type(8)));
typedef float  f32x4  __attribute__((ext_vector_type(4)));

#define MFMA16(a, b, c) __builtin_amdgcn_mfma_f32_16x16x32_bf16((a), (b), (c), 0, 0, 0)

// ---------------- K0: weight fp32 -> bf16 ----------------
__global__ __launch_bounds__(256) void k0_convert(
    const float* __restrict__ c1w, const float* __restrict__ c2w,
    const float* __restrict__ wk,  const float* __restrict__ wvv,
    bf16* __restrict__ wconv, bf16* __restrict__ wkv)
{
  const int i = blockIdx.x * 256 + threadIdx.x;   // 64 blocks
  if (i < 16384) {
    wconv[i]         = (bf16)c1w[i];
    wconv[16384 + i] = (bf16)c2w[i];
  }
  if (i < 4096) {
    wkv[i]        = (bf16)wk[i];
    wkv[4096 + i] = (bf16)wvv[i];
  }
}

// ---------------- K1: conv1x1 + LN + LN + k/v GEMM (unchanged, 155us) ----------
__global__ __launch_bounds__(256) void k1_conv_kv(
    const float* __restrict__ x1, const float* __restrict__ x2,
    const float* __restrict__ c1b, const float* __restrict__ c2b,
    const float* __restrict__ nw,  const float* __restrict__ nb,
    const float* __restrict__ niw, const float* __restrict__ nib,
    const bf16* __restrict__ wconv, const bf16* __restrict__ wkv,
    bf16* __restrict__ kbuf, bf16* __restrict__ vT)
{
  __shared__ union {
    struct { float T[64][65]; bf16 tok[64][72]; } p2; // 25,856 B
    struct { float Tk[64][65]; float Tv[64][65]; } kv;// 33,280 B
  } U;

  const int bx   = blockIdx.x;
  const int tile = bx & 15;
  const int img  = (bx >> 4) & 1;
  const int b    = bx >> 5;
  const int tid  = threadIdx.x;
  const int lane = tid & 63;
  const int wvid = tid >> 6;
  const int l15  = lane & 15;
  const int quad = lane >> 4;

  const float* xp = (img ? x2 : x1) + (size_t)b * (256 * 1024) + tile * 64;
  const bf16* wc  = wconv + img * (64 * 256);
  const int p     = wvid * 16 + l15;
  const float* xcol = xp + p + (size_t)quad * 8 * 1024;

  float xv[64];
  #pragma unroll
  for (int g = 0; g < 8; ++g)
    #pragma unroll
    for (int j = 0; j < 8; ++j)
      xv[g * 8 + j] = xcol[(size_t)(g * 32 + j) * 1024];

  f32x4 acc[4] = {{0.f,0.f,0.f,0.f},{0.f,0.f,0.f,0.f},{0.f,0.f,0.f,0.f},{0.f,0.f,0.f,0.f}};

  #pragma unroll
  for (int g = 0; g < 8; ++g) {
    bf16x8 af;
    #pragma unroll
    for (int j = 0; j < 8; ++j)
      af[j] = (bf16)xv[g * 8 + j];
    #pragma unroll
    for (int nt = 0; nt < 4; ++nt) {
      const bf16x8 bw = *(const bf16x8*)&wc[(nt * 16 + l15) * 256 + g * 32 + quad * 8];
      acc[nt] = MFMA16(af, bw, acc[nt]);
    }
  }

  {
    const float* cb = img ? c2b : c1b;
    #pragma unroll
    for (int nt = 0; nt < 4; ++nt) {
      const int d = nt * 16 + l15;
      const float bias = cb[d];
      #pragma unroll
      for (int r = 0; r < 4; ++r)
        U.p2.T[wvid * 16 + quad * 4 + r][d] = acc[nt][r] + bias;
    }
  }
  __syncthreads();

  {
    const int pix = tid >> 2, part = tid & 3;
    float xv2[16], yv[16];
    float s = 0.f, s2 = 0.f;
    #pragma unroll
    for (int i = 0; i < 16; ++i) {
      xv2[i] = U.p2.T[pix][part * 16 + i];
      s += xv2[i]; s2 += xv2[i] * xv2[i];
    }
    s  += __shfl_xor(s, 1);  s  += __shfl_xor(s, 2);
    s2 += __shfl_xor(s2, 1); s2 += __shfl_xor(s2, 2);
    float mu   = s * 0.015625f;
    float rstd = rsqrtf(s2 * 0.015625f - mu * mu + 1e-5f);
    s = 0.f; s2 = 0.f;
    #pragma unroll
    for (int i = 0; i < 16; ++i) {
      const int d = part * 16 + i;
      const float y = (xv2[i] - mu) * rstd * nw[d] + nb[d];
      yv[i] = y; s += y; s2 += y * y;
    }
    s  += __shfl_xor(s, 1);  s  += __shfl_xor(s, 2);
    s2 += __shfl_xor(s2, 1); s2 += __shfl_xor(s2, 2);
    mu   = s * 0.015625f;
    rstd = rsqrtf(s2 * 0.015625f - mu * mu + 1e-5f);
    #pragma unroll
    for (int i = 0; i < 16; ++i) {
      const int d = part * 16 + i;
      U.p2.tok[pix][d] = (bf16)((yv[i] - mu) * rstd * niw[d] + nib[d]);
    }
  }
  __syncthreads();

  f32x4 ak[4] = {{0.f,0.f,0.f,0.f},{0.f,0.f,0.f,0.f},{0.f,0.f,0.f,0.f},{0.f,0.f,0.f,0.f}};
  f32x4 av[4] = {{0.f,0.f,0.f,0.f},{0.f,0.f,0.f,0.f},{0.f,0.f,0.f,0.f},{0.f,0.f,0.f,0.f}};
  #pragma unroll
  for (int k0 = 0; k0 < 64; k0 += 32) {
    const bf16x8 af = *(const bf16x8*)&U.p2.tok[wvid * 16 + l15][k0 + quad * 8];
    #pragma unroll
    for (int nt = 0; nt < 4; ++nt) {
      const bf16x8 bk = *(const bf16x8*)&wkv[(nt * 16 + l15) * 64 + k0 + quad * 8];
      const bf16x8 bv = *(const bf16x8*)&wkv[4096 + (nt * 16 + l15) * 64 + k0 + quad * 8];
      ak[nt] = MFMA16(af, bk, ak[nt]);
      av[nt] = MFMA16(af, bv, av[nt]);
    }
  }
  __syncthreads();

  #pragma unroll
  for (int nt = 0; nt < 4; ++nt)
    #pragma unroll
    for (int r = 0; r < 4; ++r) {
      U.kv.Tk[wvid * 16 + quad * 4 + r][nt * 16 + l15] = ak[nt][r];
      U.kv.Tv[nt * 16 + l15][wvid * 16 + quad * 4 + r] = av[nt][r];
    }
  __syncthreads();
  {
    const int row = tid >> 2, dd = (tid & 3) * 16;
    const size_t kb = ((size_t)b * 2048 + img * 1024 + tile * 64) * 64;
    bf16 tb[16];
    #pragma unroll
    for (int i = 0; i < 16; ++i) tb[i] = (bf16)U.kv.Tk[row][dd + i];
    *(bf16x8*)&kbuf[kb + (size_t)row * 64 + dd]     = *(bf16x8*)&tb[0];
    *(bf16x8*)&kbuf[kb + (size_t)row * 64 + dd + 8] = *(bf16x8*)&tb[8];
    #pragma unroll
    for (int i = 0; i < 16; ++i) tb[i] = (bf16)U.kv.Tv[row][dd + i];
    const size_t vb = ((size_t)b * 64 + row) * 2048 + img * 1024 + tile * 64 + dd;
    *(bf16x8*)&vT[vb]     = *(bf16x8*)&tb[0];
    *(bf16x8*)&vT[vb + 8] = *(bf16x8*)&tb[8];
  }
}

// ---------------- kA_iter: [finish prev iter (redundant GRU+MLP)] + q + attention
// grid 1024 = 128 b * 8 chunks of 256 tokens; block 512 (8 waves, 32 tok/wave).
// it=1: slots_0 recomputed from noise; no partials read.
// it=2: slots_0 recomputed; GRU/MLP(gen gin) -> slots_1; ch==0 persists slotbuf.
// it=3: slots_1 read from slotbuf; GRU/MLP(gen gin) -> slots_2 (LDS only).
// Partials double-buffered by gen (gin != gout) -> no same-kernel read/write alias.
__global__ __launch_bounds__(512) void kA_iter(
    const bf16* __restrict__ kbuf, const bf16* __restrict__ vT,
    const float* __restrict__ smu, const float* __restrict__ slog,
    const float* __restrict__ noise,
    const float* __restrict__ nsw, const float* __restrict__ nsb,
    const float* __restrict__ nmw, const float* __restrict__ nmb,
    const float* __restrict__ Wq,
    const float* __restrict__ wih, const float* __restrict__ whh,
    const float* __restrict__ bih, const float* __restrict__ bhh,
    const float* __restrict__ w1,  const float* __restrict__ b1,
    const float* __restrict__ w2,  const float* __restrict__ b2,
    float* __restrict__ slotbuf, float* __restrict__ updf, float* __restrict__ colf,
    const int it, const int gin, const int gout)
{
  __shared__ union {
    struct { float tmp[8][66]; float slots[8][66];
             float gig[8][192]; float ghg[8][192]; float h1[8][132]; } P;  // 20,736 B
    struct { bf16 attn[16][264]; float updp[8][8][64]; float cspart[8][8]; } A; // 25,088 B
  } U;
  __shared__ bf16 qs[16][72];   // q rows 0..7, rows 8..15 zero

  const int bx  = blockIdx.x;
  const int b   = bx >> 3, ch = bx & 7;
  const int tid = threadIdx.x;
  const int lane = tid & 63, wvid = tid >> 6;
  const int l15 = lane & 15, quad = lane >> 4;
  const int s0 = tid >> 6, d0 = tid & 63;
  const int part = tid & 7, sl = (tid >> 3) & 7;

  // zero qs rows 8..15 (outside union; visible by the pre-attention barriers)
  if (tid < 288) ((uint32_t*)&qs[8][0])[tid] = 0u;

  float snorm;   // this thread's slots[s0][d0] for LN(ns)
  if (it == 1) {
    snorm = smu[d0] + expf(slog[d0]) * noise[((size_t)b * 8 + s0) * 64 + d0];
  } else {
    // reduce updates + colsums of gen gin
    {
      const float* up = updf + (((size_t)gin * 128 + b) * 8) * 512 + s0 * 64 + d0;
      float u = 0.f;
      #pragma unroll
      for (int c = 0; c < 8; ++c) u += up[c * 512];
      const float* cp = colf + (((size_t)gin * 128 + b) * 8) * 8 + s0;
      float cs = 0.f;
      #pragma unroll
      for (int c = 0; c < 8; ++c) cs += cp[c * 8];
      float sprev;
      if (it == 2) sprev = smu[d0] + expf(slog[d0]) * noise[((size_t)b * 8 + s0) * 64 + d0];
      else         sprev = slotbuf[((size_t)b * 8 + s0) * 64 + d0];
      U.P.tmp[s0][d0]   = u / cs;
      U.P.slots[s0][d0] = sprev;
    }
    __syncthreads();

    // GRU gates
    {
      float tv[8], sv[8];
      #pragma unroll
      for (int i = 0; i < 8; ++i) { tv[i] = U.P.tmp[sl][part * 8 + i]; sv[i] = U.P.slots[sl][part * 8 + i]; }
      for (int jr = 0; jr < 24; ++jr) {
        const int j = jr * 8 + wvid;
        const f32x4 wa0 = *(const f32x4*)&wih[j * 64 + part * 8];
        const f32x4 wa1 = *(const f32x4*)&wih[j * 64 + part * 8 + 4];
        const f32x4 wb0 = *(const f32x4*)&whh[j * 64 + part * 8];
        const f32x4 wb1 = *(const f32x4*)&whh[j * 64 + part * 8 + 4];
        float a = tv[0]*wa0[0] + tv[1]*wa0[1] + tv[2]*wa0[2] + tv[3]*wa0[3]
                + tv[4]*wa1[0] + tv[5]*wa1[1] + tv[6]*wa1[2] + tv[7]*wa1[3];
        float h = sv[0]*wb0[0] + sv[1]*wb0[1] + sv[2]*wb0[2] + sv[3]*wb0[3]
                + sv[4]*wb1[0] + sv[5]*wb1[1] + sv[6]*wb1[2] + sv[7]*wb1[3];
        a += __shfl_xor(a, 1); a += __shfl_xor(a, 2); a += __shfl_xor(a, 4);
        h += __shfl_xor(h, 1); h += __shfl_xor(h, 2); h += __shfl_xor(h, 4);
        if (part == 0) { U.P.gig[sl][j] = a + bih[j]; U.P.ghg[sl][j] = h + bhh[j]; }
      }
    }
    __syncthreads();

    // gate nonlinearity + slot update + LN(nm)
    {
      const float rr = 1.f / (1.f + expf(-(U.P.gig[s0][d0]      + U.P.ghg[s0][d0])));
      const float z  = 1.f / (1.f + expf(-(U.P.gig[s0][64 + d0] + U.P.ghg[s0][64 + d0])));
      const float nn = tanhf(U.P.gig[s0][128 + d0] + rr * U.P.ghg[s0][128 + d0]);
      const float snew = (1.f - z) * nn + z * U.P.slots[s0][d0];
      U.P.slots[s0][d0] = snew;
      float s = snew, s2 = snew * snew;
      #pragma unroll
      for (int m = 1; m < 64; m <<= 1) { s += __shfl_xor(s, m); s2 += __shfl_xor(s2, m); }
      const float mu = s * 0.015625f;
      const float rstd = rsqrtf(s2 * 0.015625f - mu * mu + 1e-5f);
      U.P.tmp[s0][d0] = (snew - mu) * rstd * nmw[d0] + nmb[d0];
    }
    __syncthreads();

    // MLP hidden
    {
      float tm[8];
      #pragma unroll
      for (int i = 0; i < 8; ++i) tm[i] = U.P.tmp[sl][part * 8 + i];
      for (int jr = 0; jr < 16; ++jr) {
        const int j = jr * 8 + wvid;
        const f32x4 w0 = *(const f32x4*)&w1[j * 64 + part * 8];
        const f32x4 w1v = *(const f32x4*)&w1[j * 64 + part * 8 + 4];
        float a = tm[0]*w0[0] + tm[1]*w0[1] + tm[2]*w0[2] + tm[3]*w0[3]
                + tm[4]*w1v[0] + tm[5]*w1v[1] + tm[6]*w1v[2] + tm[7]*w1v[3];
        a += __shfl_xor(a, 1); a += __shfl_xor(a, 2); a += __shfl_xor(a, 4);
        if (part == 0) U.P.h1[sl][j] = fmaxf(a + b1[j], 0.f);
      }
    }
    __syncthreads();

    // MLP out + residual
    for (int orr = 0; orr < 8; ++orr) {
      const int d = orr * 8 + wvid;
      float a = 0.f;
      #pragma unroll
      for (int i = 0; i < 4; ++i) {
        const f32x4 wv4 = *(const f32x4*)&w2[d * 128 + part * 16 + i * 4];
        a += U.P.h1[sl][part * 16 + i * 4 + 0] * wv4[0] + U.P.h1[sl][part * 16 + i * 4 + 1] * wv4[1]
           + U.P.h1[sl][part * 16 + i * 4 + 2] * wv4[2] + U.P.h1[sl][part * 16 + i * 4 + 3] * wv4[3];
      }
      a += __shfl_xor(a, 1); a += __shfl_xor(a, 2); a += __shfl_xor(a, 4);
      if (part == 0) U.P.slots[sl][d] += a + b2[d];
    }
    __syncthreads();

    snorm = U.P.slots[s0][d0];
    if (it == 2 && ch == 0)
      slotbuf[((size_t)b * 8 + s0) * 64 + d0] = snorm;   // persist slots_1 for it=3/kHead
  }

  // LN(ns) via full-wave shuffle -> tmp
  {
    float s = snorm, s2 = snorm * snorm;
    #pragma unroll
    for (int m = 1; m < 64; m <<= 1) { s += __shfl_xor(s, m); s2 += __shfl_xor(s2, m); }
    const float mu = s * 0.015625f;
    const float rstd = rsqrtf(s2 * 0.015625f - mu * mu + 1e-5f);
    U.P.tmp[s0][d0] = (snorm - mu) * rstd * nsw[d0] + nsb[d0];
  }
  __syncthreads();

  // q = LN_ns(slots) @ Wq^T * scale  -> qs (bf16)
  {
    float tm[8];
    #pragma unroll
    for (int i = 0; i < 8; ++i) tm[i] = U.P.tmp[sl][part * 8 + i];
    for (int orr = 0; orr < 8; ++orr) {
      const int d = orr * 8 + wvid;
      const f32x4 w0 = *(const f32x4*)&Wq[d * 64 + part * 8];
      const f32x4 w1v = *(const f32x4*)&Wq[d * 64 + part * 8 + 4];
      float a = tm[0]*w0[0] + tm[1]*w0[1] + tm[2]*w0[2] + tm[3]*w0[3]
              + tm[4]*w1v[0] + tm[5]*w1v[1] + tm[6]*w1v[2] + tm[7]*w1v[3];
      a += __shfl_xor(a, 1); a += __shfl_xor(a, 2); a += __shfl_xor(a, 4);
      if (part == 0) qs[sl][d] = (bf16)(a * 0.125f);
    }
  }
  __syncthreads();

  // zero attn rows 8..15 (disjoint from qs; logits below write rows 0..7)
  for (int i = tid; i < 1056; i += 512) ((uint32_t*)&U.A.attn[8][0])[i] = 0u;

  // logits (MFMA k @ q^T) + per-token softmax over s; 32 tokens per wave
  {
    float csacc = 0.f;
    const size_t tokb = (size_t)b * 2048 + ch * 256 + wvid * 32;
    #pragma unroll
    for (int mt = 0; mt < 2; ++mt) {
      const bf16* kr = kbuf + (tokb + mt * 16 + l15) * 64 + quad * 8;
      f32x4 lg = {0.f, 0.f, 0.f, 0.f};
      lg = MFMA16(*(const bf16x8*)&kr[0],  *(const bf16x8*)&qs[l15][quad * 8],      lg);
      lg = MFMA16(*(const bf16x8*)&kr[32], *(const bf16x8*)&qs[l15][32 + quad * 8], lg);
      #pragma unroll
      for (int r = 0; r < 4; ++r) {
        const float l = lg[r];
        float m = l;
        m = fmaxf(m, __shfl_xor(m, 1));
        m = fmaxf(m, __shfl_xor(m, 2));
        m = fmaxf(m, __shfl_xor(m, 4));
        const float e = expf(l - m);
        float ss = e;
        ss += __shfl_xor(ss, 1);
        ss += __shfl_xor(ss, 2);
        ss += __shfl_xor(ss, 4);
        const float at = e / ss + 1e-8f;
        if (l15 < 8) {
          const bf16 ab = (bf16)at;
          U.A.attn[l15][wvid * 32 + mt * 16 + quad * 4 + r] = ab;
          csacc += (float)ab;
        }
      }
    }
    csacc += __shfl_xor(csacc, 16);
    csacc += __shfl_xor(csacc, 32);
    if (lane < 8) U.A.cspart[wvid][lane] = csacc;
  }
  __syncthreads();

  // PV: per wave K=32 tokens
  {
    const bf16x8 afr = *(const bf16x8*)&U.A.attn[l15][wvid * 32 + quad * 8];
    const bf16* vrow = vT + (size_t)b * 131072 + (size_t)ch * 256 + wvid * 32 + quad * 8;
    const f32x4 zero4 = {0.f, 0.f, 0.f, 0.f};
    #pragma unroll
    for (int nt = 0; nt < 4; ++nt) {
      const bf16x8 bv = *(const bf16x8*)&vrow[(size_t)(nt * 16 + l15) * 2048];
      f32x4 dd = MFMA16(afr, bv, zero4);
      if (quad < 2) {
        #pragma unroll
        for (int r = 0; r < 4; ++r)
          U.A.updp[wvid][quad * 4 + r][nt * 16 + l15] = dd[r];
      }
    }
  }
  __syncthreads();

  // epilogue: reduce 8 waves -> gen gout partials
  {
    float u = 0.f;
    #pragma unroll
    for (int w = 0; w < 8; ++w) u += U.A.updp[w][s0][d0];
    updf[(((size_t)gout * 128 + b) * 8 + ch) * 512 + s0 * 64 + d0] = u;
    if (tid < 8) {
      float c = 0.f;
      #pragma unroll
      for (int w = 0; w < 8; ++w) c += U.A.cspart[w][tid];
      colf[(((size_t)gout * 128 + b) * 8 + ch) * 8 + tid] = c;
    }
  }
}

// ---------------- kHead: finish iterations 2 and 3 + head ----------------
// grid 128, block 512. pass0: slots_1(slotbuf)+gen1 -> slots_2; pass1: +gen0 -> slots_3.
__global__ __launch_bounds__(512) void kHead(
    const float* __restrict__ updf, const float* __restrict__ colf,
    const float* __restrict__ slotbuf,
    const float* __restrict__ nmw, const float* __restrict__ nmb,
    const float* __restrict__ wih, const float* __restrict__ whh,
    const float* __restrict__ bih, const float* __restrict__ bhh,
    const float* __restrict__ w1,  const float* __restrict__ b1,
    const float* __restrict__ w2,  const float* __restrict__ b2,
    const float* __restrict__ hwt, const float* __restrict__ hb,
    float* __restrict__ out)
{
  __shared__ float slots[8][66];
  __shared__ float tmp[8][66];
  __shared__ float gig[8][192], ghg[8][192];
  __shared__ float h1[8][132];
  const int b = blockIdx.x, tid = threadIdx.x;
  const int s0 = tid >> 6, d0 = tid & 63;
  const int part = tid & 7, sl = (tid >> 3) & 7, wv = tid >> 6;

  slots[s0][d0] = slotbuf[((size_t)b * 8 + s0) * 64 + d0];

  for (int pass = 0; pass < 2; ++pass) {
    const int gin = (pass == 0) ? 1 : 0;
    {
      const float* up = updf + (((size_t)gin * 128 + b) * 8) * 512 + s0 * 64 + d0;
      float u = 0.f;
      #pragma unroll
      for (int c = 0; c < 8; ++c) u += up[c * 512];
      const float* cp = colf + (((size_t)gin * 128 + b) * 8) * 8 + s0;
      float cs = 0.f;
      #pragma unroll
      for (int c = 0; c < 8; ++c) cs += cp[c * 8];
      tmp[s0][d0] = u / cs;
    }
    __syncthreads();

    {
      float tv[8], sv[8];
      #pragma unroll
      for (int i = 0; i < 8; ++i) { tv[i] = tmp[sl][part * 8 + i]; sv[i] = slots[sl][part * 8 + i]; }
      for (int jr = 0; jr < 24; ++jr) {
        const int j = jr * 8 + wv;
        const f32x4 wa0 = *(const f32x4*)&wih[j * 64 + part * 8];
        const f32x4 wa1 = *(const f32x4*)&wih[j * 64 + part * 8 + 4];
        const f32x4 wb0 = *(const f32x4*)&whh[j * 64 + part * 8];
        const f32x4 wb1 = *(const f32x4*)&whh[j * 64 + part * 8 + 4];
        float a = tv[0]*wa0[0] + tv[1]*wa0[1] + tv[2]*wa0[2] + tv[3]*wa0[3]
                + tv[4]*wa1[0] + tv[5]*wa1[1] + tv[6]*wa1[2] + tv[7]*wa1[3];
        float h = sv[0]*wb0[0] + sv[1]*wb0[1] + sv[2]*wb0[2] + sv[3]*wb0[3]
                + sv[4]*wb1[0] + sv[5]*wb1[1] + sv[6]*wb1[2] + sv[7]*wb1[3];
        a += __shfl_xor(a, 1); a += __shfl_xor(a, 2); a += __shfl_xor(a, 4);
        h += __shfl_xor(h, 1); h += __shfl_xor(h, 2); h += __shfl_xor(h, 4);
        if (part == 0) { gig[sl][j] = a + bih[j]; ghg[sl][j] = h + bhh[j]; }
      }
    }
    __syncthreads();

    {
      const float rr = 1.f / (1.f + expf(-(gig[s0][d0]      + ghg[s0][d0])));
      const float z  = 1.f / (1.f + expf(-(gig[s0][64 + d0] + ghg[s0][64 + d0])));
      const float nn = tanhf(gig[s0][128 + d0] + rr * ghg[s0][128 + d0]);
      const float snew = (1.f - z) * nn + z * slots[s0][d0];
      slots[s0][d0] = snew;
      float s = snew, s2 = snew * snew;
      #pragma unroll
      for (int m = 1; m < 64; m <<= 1) { s += __shfl_xor(s, m); s2 += __shfl_xor(s2, m); }
      const float mu = s * 0.015625f;
      const float rstd = rsqrtf(s2 * 0.015625f - mu * mu + 1e-5f);
      tmp[s0][d0] = (snew - mu) * rstd * nmw[d0] + nmb[d0];
    }
    __syncthreads();

    {
      float tm[8];
      #pragma unroll
      for (int i = 0; i < 8; ++i) tm[i] = tmp[sl][part * 8 + i];
      for (int jr = 0; jr < 16; ++jr) {
        const int j = jr * 8 + wv;
        const f32x4 w0 = *(const f32x4*)&w1[j * 64 + part * 8];
        const f32x4 w1v = *(const f32x4*)&w1[j * 64 + part * 8 + 4];
        float a = tm[0]*w0[0] + tm[1]*w0[1] + tm[2]*w0[2] + tm[3]*w0[3]
                + tm[4]*w1v[0] + tm[5]*w1v[1] + tm[6]*w1v[2] + tm[7]*w1v[3];
        a += __shfl_xor(a, 1); a += __shfl_xor(a, 2); a += __shfl_xor(a, 4);
        if (part == 0) h1[sl][j] = fmaxf(a + b1[j], 0.f);
      }
    }
    __syncthreads();

    for (int orr = 0; orr < 8; ++orr) {
      const int d = orr * 8 + wv;
      float a = 0.f;
      #pragma unroll
      for (int i = 0; i < 4; ++i) {
        const f32x4 wv4 = *(const f32x4*)&w2[d * 128 + part * 16 + i * 4];
        a += h1[sl][part * 16 + i * 4 + 0] * wv4[0] + h1[sl][part * 16 + i * 4 + 1] * wv4[1]
           + h1[sl][part * 16 + i * 4 + 2] * wv4[2] + h1[sl][part * 16 + i * 4 + 3] * wv4[3];
      }
      a += __shfl_xor(a, 1); a += __shfl_xor(a, 2); a += __shfl_xor(a, 4);
      if (part == 0) slots[sl][d] += a + b2[d];
    }
    __syncthreads();
  }

  if (tid < 64) {
    float f = 0.f;
    #pragma unroll
    for (int s = 0; s < 8; ++s) f += slots[s][tid];
    tmp[0][tid] = f * 0.125f;
  }
  __syncthreads();
  if (tid < 15) {
    float a = hb[tid];
    for (int d = 0; d < 64; ++d) a += tmp[0][d] * hwt[tid * 64 + d];
    out[b * 15 + tid] = a;
  }
}

extern "C" void kernel_launch(void* const* d_in, const int* in_sizes, int n_in,
                              void* d_out, int out_size, void* d_ws, size_t ws_size,
                              hipStream_t stream) {
  const float* x1   = (const float*)d_in[0];
  const float* x2   = (const float*)d_in[1];
  const float* c1w  = (const float*)d_in[2];
  const float* c1b  = (const float*)d_in[3];
  const float* c2w  = (const float*)d_in[4];
  const float* c2b  = (const float*)d_in[5];
  const float* nw   = (const float*)d_in[6];
  const float* nb   = (const float*)d_in[7];
  const float* niw  = (const float*)d_in[8];
  const float* nib  = (const float*)d_in[9];
  const float* nsw  = (const float*)d_in[10];
  const float* nsb  = (const float*)d_in[11];
  const float* nmw  = (const float*)d_in[12];
  const float* nmb  = (const float*)d_in[13];
  const float* smu  = (const float*)d_in[14];
  const float* slog = (const float*)d_in[15];
  const float* Wq   = (const float*)d_in[16];
  const float* Wk   = (const float*)d_in[17];
  const float* Wv   = (const float*)d_in[18];
  const float* wih  = (const float*)d_in[19];
  const float* whh  = (const float*)d_in[20];
  const float* bih  = (const float*)d_in[21];
  const float* bhh  = (const float*)d_in[22];
  const float* w1   = (const float*)d_in[23];
  const float* b1   = (const float*)d_in[24];
  const float* w2   = (const float*)d_in[25];
  const float* b2   = (const float*)d_in[26];
  const float* hwt  = (const float*)d_in[27];
  const float* hb   = (const float*)d_in[28];
  const float* noise= (const float*)d_in[29];

  char* ws = (char*)d_ws;
  bf16*  kbuf    = (bf16*)(ws);
  bf16*  vT      = (bf16*)(ws + (size_t)33554432);
  bf16*  wconv   = (bf16*)(ws + (size_t)67108864);
  bf16*  wkv     = (bf16*)(ws + (size_t)67174400);
  float* slotbuf = (float*)(ws + (size_t)67190784);
  float* updf    = (float*)(ws + (size_t)67452928);
  float* colf    = (float*)(ws + (size_t)71647232);

  k0_convert<<<dim3(64), dim3(256), 0, stream>>>(c1w, c2w, Wk, Wv, wconv, wkv);
  k1_conv_kv<<<dim3(4096), dim3(256), 0, stream>>>(x1, x2, c1b, c2b, nw, nb, niw, nib,
                                                   wconv, wkv, kbuf, vT);
  // it, gin, gout: it1 writes gen0; it2 reads gen0 writes gen1; it3 reads gen1 writes gen0
  kA_iter<<<dim3(1024), dim3(512), 0, stream>>>(kbuf, vT, smu, slog, noise, nsw, nsb,
                                                nmw, nmb, Wq, wih, whh, bih, bhh,
                                                w1, b1, w2, b2, slotbuf, updf, colf,
                                                1, 0, 0);
  kA_iter<<<dim3(1024), dim3(512), 0, stream>>>(kbuf, vT, smu, slog, noise, nsw, nsb,
                                                nmw, nmb, Wq, wih, whh, bih, bhh,
                                                w1, b1, w2, b2, slotbuf, updf, colf,
                                                2, 0, 1);
  kA_iter<<<dim3(1024), dim3(512), 0, stream>>>(kbuf, vT, smu, slog, noise, nsw, nsb,
                                                nmw, nmb, Wq, wih, whh, bih, bhh,
                                                w1, b1, w2, b2, slotbuf, updf, colf,
                                                3, 1, 0);
  kHead<<<dim3(128), dim3(512), 0, stream>>>(updf, colf, slotbuf, nmw, nmb,
                                             wih, whh, bih, bhh, w1, b1, w2, b2,
                                             hwt, hb, (float*)d_out);
}

// Round 7
// 502.983 us; speedup vs baseline: 1.3112x; 1.3112x over previous
//
#include <hip/hip_runtime.h>
#include <stdint.h>

// JointSlotFusion on MI355X (gfx950).
// ws layout (bytes):
//   kbuf   bf16[128][2048][64]   @ 0          (33,554,432)   token-major
//   vT     bf16[128][64][2048]   @ 33,554,432 (33,554,432)   d-major (transposed)
//   wconv  bf16[2][64][256]      @ 67,108,864 (65,536)
//   wkv    bf16[2][64][64]       @ 67,174,400 (16,384)
//   slotbuf f32[128][8][64]      @ 67,190,784 (262,144)
//   qbuf   bf16[128][8][64]      @ 67,452,928 (131,072)
//   updpart f32[128][16][8][64]  @ 67,584,000 (4,194,304)
//   colpart f32[128][16][8]      @ 71,778,304 (65,536)

typedef __bf16 bf16;
typedef __bf16 bf16x8 __attribute__((ext_vector_type(8)));
typedef float  f32x4  __attribute__((ext_vector_type(4)));

#define MFMA16(a, b, c) __builtin_amdgcn_mfma_f32_16x16x32_bf16((a), (b), (c), 0, 0, 0)

// ---------------- K0: weight fp32 -> bf16 ----------------
__global__ __launch_bounds__(256) void k0_convert(
    const float* __restrict__ c1w, const float* __restrict__ c2w,
    const float* __restrict__ wk,  const float* __restrict__ wvv,
    bf16* __restrict__ wconv, bf16* __restrict__ wkv)
{
  const int i = blockIdx.x * 256 + threadIdx.x;   // 64 blocks
  if (i < 16384) {
    wconv[i]         = (bf16)c1w[i];
    wconv[16384 + i] = (bf16)c2w[i];
  }
  if (i < 4096) {
    wkv[i]        = (bf16)wk[i];
    wkv[4096 + i] = (bf16)wvv[i];
  }
}

// ---------------- K1: conv1x1 + LN + LN + k/v GEMM (unchanged, 155us) ----------
__global__ __launch_bounds__(256) void k1_conv_kv(
    const float* __restrict__ x1, const float* __restrict__ x2,
    const float* __restrict__ c1b, const float* __restrict__ c2b,
    const float* __restrict__ nw,  const float* __restrict__ nb,
    const float* __restrict__ niw, const float* __restrict__ nib,
    const bf16* __restrict__ wconv, const bf16* __restrict__ wkv,
    bf16* __restrict__ kbuf, bf16* __restrict__ vT)
{
  __shared__ union {
    struct { float T[64][65]; bf16 tok[64][72]; } p2; // 25,856 B
    struct { float Tk[64][65]; float Tv[64][65]; } kv;// 33,280 B
  } U;

  const int bx   = blockIdx.x;
  const int tile = bx & 15;
  const int img  = (bx >> 4) & 1;
  const int b    = bx >> 5;
  const int tid  = threadIdx.x;
  const int lane = tid & 63;
  const int wvid = tid >> 6;
  const int l15  = lane & 15;
  const int quad = lane >> 4;

  const float* xp = (img ? x2 : x1) + (size_t)b * (256 * 1024) + tile * 64;
  const bf16* wc  = wconv + img * (64 * 256);
  const int p     = wvid * 16 + l15;
  const float* xcol = xp + p + (size_t)quad * 8 * 1024;

  float xv[64];
  #pragma unroll
  for (int g = 0; g < 8; ++g)
    #pragma unroll
    for (int j = 0; j < 8; ++j)
      xv[g * 8 + j] = xcol[(size_t)(g * 32 + j) * 1024];

  f32x4 acc[4] = {{0.f,0.f,0.f,0.f},{0.f,0.f,0.f,0.f},{0.f,0.f,0.f,0.f},{0.f,0.f,0.f,0.f}};

  #pragma unroll
  for (int g = 0; g < 8; ++g) {
    bf16x8 af;
    #pragma unroll
    for (int j = 0; j < 8; ++j)
      af[j] = (bf16)xv[g * 8 + j];
    #pragma unroll
    for (int nt = 0; nt < 4; ++nt) {
      const bf16x8 bw = *(const bf16x8*)&wc[(nt * 16 + l15) * 256 + g * 32 + quad * 8];
      acc[nt] = MFMA16(af, bw, acc[nt]);
    }
  }

  {
    const float* cb = img ? c2b : c1b;
    #pragma unroll
    for (int nt = 0; nt < 4; ++nt) {
      const int d = nt * 16 + l15;
      const float bias = cb[d];
      #pragma unroll
      for (int r = 0; r < 4; ++r)
        U.p2.T[wvid * 16 + quad * 4 + r][d] = acc[nt][r] + bias;
    }
  }
  __syncthreads();

  {
    const int pix = tid >> 2, part = tid & 3;
    float xv2[16], yv[16];
    float s = 0.f, s2 = 0.f;
    #pragma unroll
    for (int i = 0; i < 16; ++i) {
      xv2[i] = U.p2.T[pix][part * 16 + i];
      s += xv2[i]; s2 += xv2[i] * xv2[i];
    }
    s  += __shfl_xor(s, 1);  s  += __shfl_xor(s, 2);
    s2 += __shfl_xor(s2, 1); s2 += __shfl_xor(s2, 2);
    float mu   = s * 0.015625f;
    float rstd = rsqrtf(s2 * 0.015625f - mu * mu + 1e-5f);
    s = 0.f; s2 = 0.f;
    #pragma unroll
    for (int i = 0; i < 16; ++i) {
      const int d = part * 16 + i;
      const float y = (xv2[i] - mu) * rstd * nw[d] + nb[d];
      yv[i] = y; s += y; s2 += y * y;
    }
    s  += __shfl_xor(s, 1);  s  += __shfl_xor(s, 2);
    s2 += __shfl_xor(s2, 1); s2 += __shfl_xor(s2, 2);
    mu   = s * 0.015625f;
    rstd = rsqrtf(s2 * 0.015625f - mu * mu + 1e-5f);
    #pragma unroll
    for (int i = 0; i < 16; ++i) {
      const int d = part * 16 + i;
      U.p2.tok[pix][d] = (bf16)((yv[i] - mu) * rstd * niw[d] + nib[d]);
    }
  }
  __syncthreads();

  f32x4 ak[4] = {{0.f,0.f,0.f,0.f},{0.f,0.f,0.f,0.f},{0.f,0.f,0.f,0.f},{0.f,0.f,0.f,0.f}};
  f32x4 av[4] = {{0.f,0.f,0.f,0.f},{0.f,0.f,0.f,0.f},{0.f,0.f,0.f,0.f},{0.f,0.f,0.f,0.f}};
  #pragma unroll
  for (int k0 = 0; k0 < 64; k0 += 32) {
    const bf16x8 af = *(const bf16x8*)&U.p2.tok[wvid * 16 + l15][k0 + quad * 8];
    #pragma unroll
    for (int nt = 0; nt < 4; ++nt) {
      const bf16x8 bk = *(const bf16x8*)&wkv[(nt * 16 + l15) * 64 + k0 + quad * 8];
      const bf16x8 bv = *(const bf16x8*)&wkv[4096 + (nt * 16 + l15) * 64 + k0 + quad * 8];
      ak[nt] = MFMA16(af, bk, ak[nt]);
      av[nt] = MFMA16(af, bv, av[nt]);
    }
  }
  __syncthreads();

  #pragma unroll
  for (int nt = 0; nt < 4; ++nt)
    #pragma unroll
    for (int r = 0; r < 4; ++r) {
      U.kv.Tk[wvid * 16 + quad * 4 + r][nt * 16 + l15] = ak[nt][r];
      U.kv.Tv[nt * 16 + l15][wvid * 16 + quad * 4 + r] = av[nt][r];
    }
  __syncthreads();
  {
    const int row = tid >> 2, dd = (tid & 3) * 16;
    const size_t kb = ((size_t)b * 2048 + img * 1024 + tile * 64) * 64;
    bf16 tb[16];
    #pragma unroll
    for (int i = 0; i < 16; ++i) tb[i] = (bf16)U.kv.Tk[row][dd + i];
    *(bf16x8*)&kbuf[kb + (size_t)row * 64 + dd]     = *(bf16x8*)&tb[0];
    *(bf16x8*)&kbuf[kb + (size_t)row * 64 + dd + 8] = *(bf16x8*)&tb[8];
    #pragma unroll
    for (int i = 0; i < 16; ++i) tb[i] = (bf16)U.kv.Tv[row][dd + i];
    const size_t vb = ((size_t)b * 64 + row) * 2048 + img * 1024 + tile * 64 + dd;
    *(bf16x8*)&vT[vb]     = *(bf16x8*)&tb[0];
    *(bf16x8*)&vT[vb + 8] = *(bf16x8*)&tb[8];
  }
}

// ---------------- kS0: slots init + q0 ----------------
__global__ __launch_bounds__(512) void kS0(
    const float* __restrict__ smu, const float* __restrict__ slog,
    const float* __restrict__ noise,
    const float* __restrict__ nsw, const float* __restrict__ nsb,
    const float* __restrict__ Wq,
    float* __restrict__ slotbuf, bf16* __restrict__ qbuf)
{
  __shared__ float tmp[8][66];
  const int b = blockIdx.x, tid = threadIdx.x;
  const int s0 = tid >> 6, d0 = tid & 63;
  const int part = tid & 7, sl = (tid >> 3) & 7, wv = tid >> 6;

  const float sval = smu[d0] + expf(slog[d0]) * noise[((size_t)b * 8 + s0) * 64 + d0];
  slotbuf[((size_t)b * 8 + s0) * 64 + d0] = sval;
  float s = sval, s2 = sval * sval;
  #pragma unroll
  for (int m = 1; m < 64; m <<= 1) { s += __shfl_xor(s, m); s2 += __shfl_xor(s2, m); }
  const float mu = s * 0.015625f;
  const float rstd = rsqrtf(s2 * 0.015625f - mu * mu + 1e-5f);
  tmp[s0][d0] = (sval - mu) * rstd * nsw[d0] + nsb[d0];
  __syncthreads();

  float tm[8];
  #pragma unroll
  for (int i = 0; i < 8; ++i) tm[i] = tmp[sl][part * 8 + i];
  for (int orr = 0; orr < 8; ++orr) {
    const int d = orr * 8 + wv;
    const f32x4 w0 = *(const f32x4*)&Wq[d * 64 + part * 8];
    const f32x4 w1v = *(const f32x4*)&Wq[d * 64 + part * 8 + 4];
    float a = tm[0]*w0[0] + tm[1]*w0[1] + tm[2]*w0[2] + tm[3]*w0[3]
            + tm[4]*w1v[0] + tm[5]*w1v[1] + tm[6]*w1v[2] + tm[7]*w1v[3];
    a += __shfl_xor(a, 1); a += __shfl_xor(a, 2); a += __shfl_xor(a, 4);
    if (part == 0) qbuf[((size_t)b * 8 + sl) * 64 + d] = (bf16)(a * 0.125f);
  }
}

// ---------------- kA: logits + softmax + PV via MFMA ----------------
// grid 2048 = 128 b * 16 chunks of 128 tokens; block 256 (4 waves, 32 tok/wave)
__global__ __launch_bounds__(256) void kA(
    const bf16* __restrict__ kbuf, const bf16* __restrict__ vT,
    const bf16* __restrict__ qbuf,
    float* __restrict__ updpart, float* __restrict__ colpart)
{
  __shared__ bf16  qs[16][72];       // q rows 0..7, rows 8..15 zero
  __shared__ bf16  attn_b[16][136];  // [s][tok] bf16, rows 8..15 zero
  __shared__ float updp[4][8][64];
  __shared__ float cspart[4][8];

  const int bx  = blockIdx.x;
  const int b   = bx >> 4, ch = bx & 15;
  const int tid = threadIdx.x;
  const int lane = tid & 63, wvid = tid >> 6;
  const int l15 = lane & 15, quad = lane >> 4;
  const size_t tokbase = (size_t)b * 2048 + ch * 128;

  if (tid < 64) {
    const int s = tid >> 3, o = (tid & 7) * 8;
    *(bf16x8*)&qs[s][o] = *(const bf16x8*)&qbuf[((size_t)b * 8 + s) * 64 + o];
  } else if (tid < 128) {
    const int s = 8 + ((tid - 64) >> 3), o = ((tid - 64) & 7) * 8;
    uint32_t* zp = (uint32_t*)&qs[s][o];
    zp[0] = 0u; zp[1] = 0u; zp[2] = 0u; zp[3] = 0u;
  }
  {
    uint32_t* az = (uint32_t*)&attn_b[8][0];   // zero rows 8..15 (8*136 hw = 544 dw)
    for (int i = tid; i < 544; i += 256) az[i] = 0u;
  }
  __syncthreads();

  // logits (MFMA k @ q^T) + per-token softmax over s
  {
    float cs = 0.f;
    #pragma unroll
    for (int mt = 0; mt < 2; ++mt) {
      const int t0 = wvid * 32 + mt * 16;
      const bf16* kr = kbuf + (tokbase + t0 + l15) * 64 + quad * 8;
      f32x4 lg = {0.f, 0.f, 0.f, 0.f};
      lg = MFMA16(*(const bf16x8*)&kr[0],  *(const bf16x8*)&qs[l15][quad * 8],      lg);
      lg = MFMA16(*(const bf16x8*)&kr[32], *(const bf16x8*)&qs[l15][32 + quad * 8], lg);
      #pragma unroll
      for (int r = 0; r < 4; ++r) {
        const float l = lg[r];
        float m = l;
        m = fmaxf(m, __shfl_xor(m, 1));
        m = fmaxf(m, __shfl_xor(m, 2));
        m = fmaxf(m, __shfl_xor(m, 4));
        const float e = expf(l - m);
        float ss = e;
        ss += __shfl_xor(ss, 1);
        ss += __shfl_xor(ss, 2);
        ss += __shfl_xor(ss, 4);
        const float at = e / ss + 1e-8f;
        if (l15 < 8) {
          const bf16 ab = (bf16)at;
          attn_b[l15][t0 + quad * 4 + r] = ab;
          cs += (float)ab;
        }
      }
    }
    cs += __shfl_xor(cs, 16);
    cs += __shfl_xor(cs, 32);
    if (lane < 8) cspart[wvid][lane] = cs;
  }
  __syncthreads();

  // PV: per wave K=32 tokens; A = attn (A-frag-ready), B = vT rows from global
  {
    const bf16x8 afr = *(const bf16x8*)&attn_b[l15][wvid * 32 + quad * 8];
    const bf16* vrow = vT + (size_t)b * 131072 + (size_t)ch * 128 + wvid * 32 + quad * 8;
    const f32x4 zero4 = {0.f, 0.f, 0.f, 0.f};
    #pragma unroll
    for (int nt = 0; nt < 4; ++nt) {
      const bf16x8 bv = *(const bf16x8*)&vrow[(size_t)(nt * 16 + l15) * 2048];
      f32x4 dd = MFMA16(afr, bv, zero4);
      if (quad < 2) {
        #pragma unroll
        for (int r = 0; r < 4; ++r)
          updp[wvid][quad * 4 + r][nt * 16 + l15] = dd[r];
      }
    }
  }
  __syncthreads();

  {
    const float* up = &updp[0][0][0];
    float* og = updpart + ((size_t)b * 16 + ch) * 512;
    for (int o = tid; o < 512; o += 256)
      og[o] = up[o] + up[o + 512] + up[o + 1024] + up[o + 1536];
    if (tid < 8)
      colpart[((size_t)b * 16 + ch) * 8 + tid] =
        cspart[0][tid] + cspart[1][tid] + cspart[2][tid] + cspart[3][tid];
  }
}

// ---------------- kB: reduce + GRU + MLP + next-q / head ----------------
// grid 128, block 1024 (16 waves): halves every serial j-loop (GRU 24->12,
// MLP-hidden 16->8, MLP-out/next-q 8->4) and doubles waves/SIMD (2->4) for
// latency hiding. Phases over the 512 (slot,d) pairs guard tid<512 (waves 0-7).
__global__ __launch_bounds__(1024) void kB(
    const float* __restrict__ updpart, const float* __restrict__ colpart,
    float* __restrict__ slotbuf, bf16* __restrict__ qbuf,
    const float* __restrict__ nsw, const float* __restrict__ nsb,
    const float* __restrict__ nmw, const float* __restrict__ nmb,
    const float* __restrict__ Wq,
    const float* __restrict__ wih, const float* __restrict__ whh,
    const float* __restrict__ bih, const float* __restrict__ bhh,
    const float* __restrict__ w1,  const float* __restrict__ b1,
    const float* __restrict__ w2,  const float* __restrict__ b2,
    const float* __restrict__ hwt, const float* __restrict__ hb,
    float* __restrict__ out, const int last)
{
  __shared__ float slots[8][66];
  __shared__ float tmp[8][66];
  __shared__ float gig[8][192], ghg[8][192];
  __shared__ float h1[8][132];
  const int b = blockIdx.x, tid = threadIdx.x;
  const int s0 = (tid >> 6) & 7, d0 = tid & 63;    // valid when tid<512
  const int part = tid & 7, sl = (tid >> 3) & 7;
  const int wv16 = tid >> 6;                       // wave id 0..15

  if (tid < 512) {
    const float* up = updpart + (size_t)b * 8192 + s0 * 64 + d0;
    float u = 0.f;
    #pragma unroll
    for (int ch = 0; ch < 16; ++ch) u += up[ch * 512];
    const float* cp = colpart + (size_t)b * 128 + s0;
    float cs = 0.f;
    #pragma unroll
    for (int ch = 0; ch < 16; ++ch) cs += cp[ch * 8];
    tmp[s0][d0] = u / cs;
    slots[s0][d0] = slotbuf[((size_t)b * 8 + s0) * 64 + d0];
  }
  __syncthreads();

  // GRU gates: 16 waves, j = jr*16 + wv16, jr < 12
  {
    float tv[8], sv[8];
    #pragma unroll
    for (int i = 0; i < 8; ++i) { tv[i] = tmp[sl][part * 8 + i]; sv[i] = slots[sl][part * 8 + i]; }
    for (int jr = 0; jr < 12; ++jr) {
      const int j = jr * 16 + wv16;
      const f32x4 wa0 = *(const f32x4*)&wih[j * 64 + part * 8];
      const f32x4 wa1 = *(const f32x4*)&wih[j * 64 + part * 8 + 4];
      const f32x4 wb0 = *(const f32x4*)&whh[j * 64 + part * 8];
      const f32x4 wb1 = *(const f32x4*)&whh[j * 64 + part * 8 + 4];
      float a = tv[0]*wa0[0] + tv[1]*wa0[1] + tv[2]*wa0[2] + tv[3]*wa0[3]
              + tv[4]*wa1[0] + tv[5]*wa1[1] + tv[6]*wa1[2] + tv[7]*wa1[3];
      float h = sv[0]*wb0[0] + sv[1]*wb0[1] + sv[2]*wb0[2] + sv[3]*wb0[3]
              + sv[4]*wb1[0] + sv[5]*wb1[1] + sv[6]*wb1[2] + sv[7]*wb1[3];
      a += __shfl_xor(a, 1); a += __shfl_xor(a, 2); a += __shfl_xor(a, 4);
      h += __shfl_xor(h, 1); h += __shfl_xor(h, 2); h += __shfl_xor(h, 4);
      if (part == 0) { gig[sl][j] = a + bih[j]; ghg[sl][j] = h + bhh[j]; }
    }
  }
  __syncthreads();

  if (tid < 512) {
    const float r  = 1.f / (1.f + expf(-(gig[s0][d0]       + ghg[s0][d0])));
    const float z  = 1.f / (1.f + expf(-(gig[s0][64 + d0]  + ghg[s0][64 + d0])));
    const float nn = tanhf(gig[s0][128 + d0] + r * ghg[s0][128 + d0]);
    const float snew = (1.f - z) * nn + z * slots[s0][d0];
    slots[s0][d0] = snew;
    float s = snew, s2 = snew * snew;
    #pragma unroll
    for (int m = 1; m < 64; m <<= 1) { s += __shfl_xor(s, m); s2 += __shfl_xor(s2, m); }
    const float mu = s * 0.015625f;
    const float rstd = rsqrtf(s2 * 0.015625f - mu * mu + 1e-5f);
    tmp[s0][d0] = (snew - mu) * rstd * nmw[d0] + nmb[d0];
  }
  __syncthreads();

  // MLP hidden: j = jr*16 + wv16, jr < 8
  {
    float tm[8];
    #pragma unroll
    for (int i = 0; i < 8; ++i) tm[i] = tmp[sl][part * 8 + i];
    for (int jr = 0; jr < 8; ++jr) {
      const int j = jr * 16 + wv16;
      const f32x4 w0 = *(const f32x4*)&w1[j * 64 + part * 8];
      const f32x4 w1v = *(const f32x4*)&w1[j * 64 + part * 8 + 4];
      float a = tm[0]*w0[0] + tm[1]*w0[1] + tm[2]*w0[2] + tm[3]*w0[3]
              + tm[4]*w1v[0] + tm[5]*w1v[1] + tm[6]*w1v[2] + tm[7]*w1v[3];
      a += __shfl_xor(a, 1); a += __shfl_xor(a, 2); a += __shfl_xor(a, 4);
      if (part == 0) h1[sl][j] = fmaxf(a + b1[j], 0.f);
    }
  }
  __syncthreads();

  // MLP out + residual: d = orr*16 + wv16, orr < 4
  for (int orr = 0; orr < 4; ++orr) {
    const int d = orr * 16 + wv16;
    float a = 0.f;
    #pragma unroll
    for (int i = 0; i < 4; ++i) {
      const f32x4 wv4 = *(const f32x4*)&w2[d * 128 + part * 16 + i * 4];
      a += h1[sl][part * 16 + i * 4 + 0] * wv4[0] + h1[sl][part * 16 + i * 4 + 1] * wv4[1]
         + h1[sl][part * 16 + i * 4 + 2] * wv4[2] + h1[sl][part * 16 + i * 4 + 3] * wv4[3];
    }
    a += __shfl_xor(a, 1); a += __shfl_xor(a, 2); a += __shfl_xor(a, 4);
    if (part == 0) slots[sl][d] += a + b2[d];
  }
  __syncthreads();

  if (!last) {
    if (tid < 512) {
      const float sfin = slots[s0][d0];
      slotbuf[((size_t)b * 8 + s0) * 64 + d0] = sfin;
      float s = sfin, s2 = sfin * sfin;
      #pragma unroll
      for (int m = 1; m < 64; m <<= 1) { s += __shfl_xor(s, m); s2 += __shfl_xor(s2, m); }
      const float mu = s * 0.015625f;
      const float rstd = rsqrtf(s2 * 0.015625f - mu * mu + 1e-5f);
      tmp[s0][d0] = (sfin - mu) * rstd * nsw[d0] + nsb[d0];
    }
    __syncthreads();
    float tm[8];
    #pragma unroll
    for (int i = 0; i < 8; ++i) tm[i] = tmp[sl][part * 8 + i];
    for (int orr = 0; orr < 4; ++orr) {
      const int d = orr * 16 + wv16;
      const f32x4 w0 = *(const f32x4*)&Wq[d * 64 + part * 8];
      const f32x4 w1v = *(const f32x4*)&Wq[d * 64 + part * 8 + 4];
      float a = tm[0]*w0[0] + tm[1]*w0[1] + tm[2]*w0[2] + tm[3]*w0[3]
              + tm[4]*w1v[0] + tm[5]*w1v[1] + tm[6]*w1v[2] + tm[7]*w1v[3];
      a += __shfl_xor(a, 1); a += __shfl_xor(a, 2); a += __shfl_xor(a, 4);
      if (part == 0) qbuf[((size_t)b * 8 + sl) * 64 + d] = (bf16)(a * 0.125f);
    }
  } else {
    if (tid < 512) slotbuf[((size_t)b * 8 + s0) * 64 + d0] = slots[s0][d0];
    if (tid < 64) {
      float f = 0.f;
      #pragma unroll
      for (int s = 0; s < 8; ++s) f += slots[s][tid];
      tmp[0][tid] = f * 0.125f;
    }
    __syncthreads();
    if (tid < 15) {
      float a = hb[tid];
      for (int d = 0; d < 64; ++d) a += tmp[0][d] * hwt[tid * 64 + d];
      out[b * 15 + tid] = a;
    }
  }
}

extern "C" void kernel_launch(void* const* d_in, const int* in_sizes, int n_in,
                              void* d_out, int out_size, void* d_ws, size_t ws_size,
                              hipStream_t stream) {
  const float* x1   = (const float*)d_in[0];
  const float* x2   = (const float*)d_in[1];
  const float* c1w  = (const float*)d_in[2];
  const float* c1b  = (const float*)d_in[3];
  const float* c2w  = (const float*)d_in[4];
  const float* c2b  = (const float*)d_in[5];
  const float* nw   = (const float*)d_in[6];
  const float* nb   = (const float*)d_in[7];
  const float* niw  = (const float*)d_in[8];
  const float* nib  = (const float*)d_in[9];
  const float* nsw  = (const float*)d_in[10];
  const float* nsb  = (const float*)d_in[11];
  const float* nmw  = (const float*)d_in[12];
  const float* nmb  = (const float*)d_in[13];
  const float* smu  = (const float*)d_in[14];
  const float* slog = (const float*)d_in[15];
  const float* Wq   = (const float*)d_in[16];
  const float* Wk   = (const float*)d_in[17];
  const float* Wv   = (const float*)d_in[18];
  const float* wih  = (const float*)d_in[19];
  const float* whh  = (const float*)d_in[20];
  const float* bih  = (const float*)d_in[21];
  const float* bhh  = (const float*)d_in[22];
  const float* w1   = (const float*)d_in[23];
  const float* b1   = (const float*)d_in[24];
  const float* w2   = (const float*)d_in[25];
  const float* b2   = (const float*)d_in[26];
  const float* hwt  = (const float*)d_in[27];
  const float* hb   = (const float*)d_in[28];
  const float* noise= (const float*)d_in[29];

  char* ws = (char*)d_ws;
  bf16*  kbuf    = (bf16*)(ws);
  bf16*  vT      = (bf16*)(ws + (size_t)33554432);
  bf16*  wconv   = (bf16*)(ws + (size_t)67108864);
  bf16*  wkv     = (bf16*)(ws + (size_t)67174400);
  float* slotbuf = (float*)(ws + (size_t)67190784);
  bf16*  qbuf    = (bf16*)(ws + (size_t)67452928);
  float* updpart = (float*)(ws + (size_t)67584000);
  float* colpart = (float*)(ws + (size_t)71778304);

  k0_convert<<<dim3(64), dim3(256), 0, stream>>>(c1w, c2w, Wk, Wv, wconv, wkv);
  k1_conv_kv<<<dim3(4096), dim3(256), 0, stream>>>(x1, x2, c1b, c2b, nw, nb, niw, nib,
                                                   wconv, wkv, kbuf, vT);
  kS0<<<dim3(128), dim3(512), 0, stream>>>(smu, slog, noise, nsw, nsb, Wq, slotbuf, qbuf);
  for (int it = 0; it < 3; ++it) {
    kA<<<dim3(2048), dim3(256), 0, stream>>>(kbuf, vT, qbuf, updpart, colpart);
    kB<<<dim3(128), dim3(1024), 0, stream>>>(updpart, colpart, slotbuf, qbuf,
                                             nsw, nsb, nmw, nmb, Wq,
                                             wih, whh, bih, bhh, w1, b1, w2, b2,
                                             hwt, hb, (float*)d_out, (it == 2) ? 1 : 0);
  }
}

// Round 8
// 499.762 us; speedup vs baseline: 1.3197x; 1.0064x over previous
//
#include <hip/hip_runtime.h>
#include <stdint.h>

// JointSlotFusion on MI355X (gfx950).
// ws layout (bytes):
//   kbuf   bf16[128][2048][64]   @ 0          (33,554,432)   token-major
//   vT     bf16[128][64][2048]   @ 33,554,432 (33,554,432)   d-major (transposed)
//   wconv  bf16[2][64][256]      @ 67,108,864 (65,536)
//   wkv    bf16[2][64][64]       @ 67,174,400 (16,384)
//   slotbuf f32[128][8][64]      @ 67,190,784 (262,144)
//   qbuf   bf16[128][8][64]      @ 67,452,928 (131,072)
//   updpart f32[128][16][8][64]  @ 67,584,000 (4,194,304)
//   colpart f32[128][16][8]      @ 71,778,304 (65,536)

typedef __bf16 bf16;
typedef __bf16 bf16x8 __attribute__((ext_vector_type(8)));
typedef float  f32x4  __attribute__((ext_vector_type(4)));

#define MFMA16(a, b, c) __builtin_amdgcn_mfma_f32_16x16x32_bf16((a), (b), (c), 0, 0, 0)

// ---------------- K0: weight fp32 -> bf16 ----------------
__global__ __launch_bounds__(256) void k0_convert(
    const float* __restrict__ c1w, const float* __restrict__ c2w,
    const float* __restrict__ wk,  const float* __restrict__ wvv,
    bf16* __restrict__ wconv, bf16* __restrict__ wkv)
{
  const int i = blockIdx.x * 256 + threadIdx.x;   // 64 blocks
  if (i < 16384) {
    wconv[i]         = (bf16)c1w[i];
    wconv[16384 + i] = (bf16)c2w[i];
  }
  if (i < 4096) {
    wkv[i]        = (bf16)wk[i];
    wkv[4096 + i] = (bf16)wvv[i];
  }
}

// ---------------- K1: conv1x1 + LN + LN + k/v GEMM ----------------
// grid 4096 = 128 b * 2 img * 16 pixel-tiles of 64; block 256 (4 waves)
// LDS slimmed to ONE 16,640B buffer reused sequentially (conv park -> bf16
// tokens alias -> k repack -> v repack). Previous 33,280B union capped
// residency at ~2-3 blocks/CU (Occupancy 29%) -> in-flight bytes below the
// HBM BW-delay product -> 1.3 TB/s. 16.6KB -> ~7 blocks/CU (28 waves),
// trading 2 extra barriers for 3x latency-hiding capacity.
__global__ __launch_bounds__(256) void k1_conv_kv(
    const float* __restrict__ x1, const float* __restrict__ x2,
    const float* __restrict__ c1b, const float* __restrict__ c2b,
    const float* __restrict__ nw,  const float* __restrict__ nb,
    const float* __restrict__ niw, const float* __restrict__ nib,
    const bf16* __restrict__ wconv, const bf16* __restrict__ wkv,
    bf16* __restrict__ kbuf, bf16* __restrict__ vT)
{
  __shared__ union {
    float T[64][65];    // 16,640 B: conv park / k repack / v repack
    bf16  tok[64][72];  //  9,216 B alias: LN'd tokens
  } U;

  const int bx   = blockIdx.x;
  const int tile = bx & 15;
  const int img  = (bx >> 4) & 1;
  const int b    = bx >> 5;
  const int tid  = threadIdx.x;
  const int lane = tid & 63;
  const int wvid = tid >> 6;
  const int l15  = lane & 15;
  const int quad = lane >> 4;

  const float* xp = (img ? x2 : x1) + (size_t)b * (256 * 1024) + tile * 64;
  const bf16* wc  = wconv + img * (64 * 256);
  const int p     = wvid * 16 + l15;
  const float* xcol = xp + p + (size_t)quad * 8 * 1024;

  float xv[64];
  #pragma unroll
  for (int g = 0; g < 8; ++g)
    #pragma unroll
    for (int j = 0; j < 8; ++j)
      xv[g * 8 + j] = xcol[(size_t)(g * 32 + j) * 1024];

  f32x4 acc[4] = {{0.f,0.f,0.f,0.f},{0.f,0.f,0.f,0.f},{0.f,0.f,0.f,0.f},{0.f,0.f,0.f,0.f}};

  #pragma unroll
  for (int g = 0; g < 8; ++g) {
    bf16x8 af;
    #pragma unroll
    for (int j = 0; j < 8; ++j)
      af[j] = (bf16)xv[g * 8 + j];
    #pragma unroll
    for (int nt = 0; nt < 4; ++nt) {
      const bf16x8 bw = *(const bf16x8*)&wc[(nt * 16 + l15) * 256 + g * 32 + quad * 8];
      acc[nt] = MFMA16(af, bw, acc[nt]);
    }
  }

  // bias + park in fp32 tile
  {
    const float* cb = img ? c2b : c1b;
    #pragma unroll
    for (int nt = 0; nt < 4; ++nt) {
      const int d = nt * 16 + l15;
      const float bias = cb[d];
      #pragma unroll
      for (int r = 0; r < 4; ++r)
        U.T[wvid * 16 + quad * 4 + r][d] = acc[nt][r] + bias;
    }
  }
  __syncthreads();

  // Double LayerNorm -> bf16 tokens (tok aliases T: read-to-regs, barrier, write)
  {
    const int pix = tid >> 2, part = tid & 3;
    float xv2[16], yv[16];
    float s = 0.f, s2 = 0.f;
    #pragma unroll
    for (int i = 0; i < 16; ++i) {
      xv2[i] = U.T[pix][part * 16 + i];
      s += xv2[i]; s2 += xv2[i] * xv2[i];
    }
    __syncthreads();   // all T reads done before tok overwrites the buffer
    s  += __shfl_xor(s, 1);  s  += __shfl_xor(s, 2);
    s2 += __shfl_xor(s2, 1); s2 += __shfl_xor(s2, 2);
    float mu   = s * 0.015625f;
    float rstd = rsqrtf(s2 * 0.015625f - mu * mu + 1e-5f);
    s = 0.f; s2 = 0.f;
    #pragma unroll
    for (int i = 0; i < 16; ++i) {
      const int d = part * 16 + i;
      const float y = (xv2[i] - mu) * rstd * nw[d] + nb[d];
      yv[i] = y; s += y; s2 += y * y;
    }
    s  += __shfl_xor(s, 1);  s  += __shfl_xor(s, 2);
    s2 += __shfl_xor(s2, 1); s2 += __shfl_xor(s2, 2);
    mu   = s * 0.015625f;
    rstd = rsqrtf(s2 * 0.015625f - mu * mu + 1e-5f);
    #pragma unroll
    for (int i = 0; i < 16; ++i) {
      const int d = part * 16 + i;
      U.tok[pix][d] = (bf16)((yv[i] - mu) * rstd * niw[d] + nib[d]);
    }
  }
  __syncthreads();

  // k/v GEMMs: K=64
  f32x4 ak[4] = {{0.f,0.f,0.f,0.f},{0.f,0.f,0.f,0.f},{0.f,0.f,0.f,0.f},{0.f,0.f,0.f,0.f}};
  f32x4 av[4] = {{0.f,0.f,0.f,0.f},{0.f,0.f,0.f,0.f},{0.f,0.f,0.f,0.f},{0.f,0.f,0.f,0.f}};
  #pragma unroll
  for (int k0 = 0; k0 < 64; k0 += 32) {
    const bf16x8 af = *(const bf16x8*)&U.tok[wvid * 16 + l15][k0 + quad * 8];
    #pragma unroll
    for (int nt = 0; nt < 4; ++nt) {
      const bf16x8 bk = *(const bf16x8*)&wkv[(nt * 16 + l15) * 64 + k0 + quad * 8];
      const bf16x8 bv = *(const bf16x8*)&wkv[4096 + (nt * 16 + l15) * 64 + k0 + quad * 8];
      ak[nt] = MFMA16(af, bk, ak[nt]);
      av[nt] = MFMA16(af, bv, av[nt]);
    }
  }
  __syncthreads();   // tok reads done -> buffer free for k repack

  // k repack (pixel-major) + store
  #pragma unroll
  for (int nt = 0; nt < 4; ++nt)
    #pragma unroll
    for (int r = 0; r < 4; ++r)
      U.T[wvid * 16 + quad * 4 + r][nt * 16 + l15] = ak[nt][r];
  __syncthreads();
  {
    const int row = tid >> 2, dd = (tid & 3) * 16;
    const size_t kb = ((size_t)b * 2048 + img * 1024 + tile * 64) * 64;
    bf16 tb[16];
    #pragma unroll
    for (int i = 0; i < 16; ++i) tb[i] = (bf16)U.T[row][dd + i];
    *(bf16x8*)&kbuf[kb + (size_t)row * 64 + dd]     = *(bf16x8*)&tb[0];
    *(bf16x8*)&kbuf[kb + (size_t)row * 64 + dd + 8] = *(bf16x8*)&tb[8];
  }
  __syncthreads();   // k reads done -> buffer free for v repack

  // v repack (d-major) + store
  #pragma unroll
  for (int nt = 0; nt < 4; ++nt)
    #pragma unroll
    for (int r = 0; r < 4; ++r)
      U.T[nt * 16 + l15][wvid * 16 + quad * 4 + r] = av[nt][r];
  __syncthreads();
  {
    const int row = tid >> 2, dd = (tid & 3) * 16;
    bf16 tb[16];
    #pragma unroll
    for (int i = 0; i < 16; ++i) tb[i] = (bf16)U.T[row][dd + i];
    const size_t vb = ((size_t)b * 64 + row) * 2048 + img * 1024 + tile * 64 + dd;
    *(bf16x8*)&vT[vb]     = *(bf16x8*)&tb[0];
    *(bf16x8*)&vT[vb + 8] = *(bf16x8*)&tb[8];
  }
}

// ---------------- kS0: slots init + q0 ----------------
__global__ __launch_bounds__(512) void kS0(
    const float* __restrict__ smu, const float* __restrict__ slog,
    const float* __restrict__ noise,
    const float* __restrict__ nsw, const float* __restrict__ nsb,
    const float* __restrict__ Wq,
    float* __restrict__ slotbuf, bf16* __restrict__ qbuf)
{
  __shared__ float tmp[8][66];
  const int b = blockIdx.x, tid = threadIdx.x;
  const int s0 = tid >> 6, d0 = tid & 63;
  const int part = tid & 7, sl = (tid >> 3) & 7, wv = tid >> 6;

  const float sval = smu[d0] + expf(slog[d0]) * noise[((size_t)b * 8 + s0) * 64 + d0];
  slotbuf[((size_t)b * 8 + s0) * 64 + d0] = sval;
  float s = sval, s2 = sval * sval;
  #pragma unroll
  for (int m = 1; m < 64; m <<= 1) { s += __shfl_xor(s, m); s2 += __shfl_xor(s2, m); }
  const float mu = s * 0.015625f;
  const float rstd = rsqrtf(s2 * 0.015625f - mu * mu + 1e-5f);
  tmp[s0][d0] = (sval - mu) * rstd * nsw[d0] + nsb[d0];
  __syncthreads();

  float tm[8];
  #pragma unroll
  for (int i = 0; i < 8; ++i) tm[i] = tmp[sl][part * 8 + i];
  for (int orr = 0; orr < 8; ++orr) {
    const int d = orr * 8 + wv;
    const f32x4 w0 = *(const f32x4*)&Wq[d * 64 + part * 8];
    const f32x4 w1v = *(const f32x4*)&Wq[d * 64 + part * 8 + 4];
    float a = tm[0]*w0[0] + tm[1]*w0[1] + tm[2]*w0[2] + tm[3]*w0[3]
            + tm[4]*w1v[0] + tm[5]*w1v[1] + tm[6]*w1v[2] + tm[7]*w1v[3];
    a += __shfl_xor(a, 1); a += __shfl_xor(a, 2); a += __shfl_xor(a, 4);
    if (part == 0) qbuf[((size_t)b * 8 + sl) * 64 + d] = (bf16)(a * 0.125f);
  }
}

// ---------------- kA: logits + softmax + PV via MFMA ----------------
// grid 2048 = 128 b * 16 chunks of 128 tokens; block 256 (4 waves, 32 tok/wave)
__global__ __launch_bounds__(256) void kA(
    const bf16* __restrict__ kbuf, const bf16* __restrict__ vT,
    const bf16* __restrict__ qbuf,
    float* __restrict__ updpart, float* __restrict__ colpart)
{
  __shared__ bf16  qs[16][72];       // q rows 0..7, rows 8..15 zero
  __shared__ bf16  attn_b[16][136];  // [s][tok] bf16, rows 8..15 zero
  __shared__ float updp[4][8][64];
  __shared__ float cspart[4][8];

  const int bx  = blockIdx.x;
  const int b   = bx >> 4, ch = bx & 15;
  const int tid = threadIdx.x;
  const int lane = tid & 63, wvid = tid >> 6;
  const int l15 = lane & 15, quad = lane >> 4;
  const size_t tokbase = (size_t)b * 2048 + ch * 128;

  if (tid < 64) {
    const int s = tid >> 3, o = (tid & 7) * 8;
    *(bf16x8*)&qs[s][o] = *(const bf16x8*)&qbuf[((size_t)b * 8 + s) * 64 + o];
  } else if (tid < 128) {
    const int s = 8 + ((tid - 64) >> 3), o = ((tid - 64) & 7) * 8;
    uint32_t* zp = (uint32_t*)&qs[s][o];
    zp[0] = 0u; zp[1] = 0u; zp[2] = 0u; zp[3] = 0u;
  }
  {
    uint32_t* az = (uint32_t*)&attn_b[8][0];   // zero rows 8..15 (8*136 hw = 544 dw)
    for (int i = tid; i < 544; i += 256) az[i] = 0u;
  }
  __syncthreads();

  // logits (MFMA k @ q^T) + per-token softmax over s
  {
    float cs = 0.f;
    #pragma unroll
    for (int mt = 0; mt < 2; ++mt) {
      const int t0 = wvid * 32 + mt * 16;
      const bf16* kr = kbuf + (tokbase + t0 + l15) * 64 + quad * 8;
      f32x4 lg = {0.f, 0.f, 0.f, 0.f};
      lg = MFMA16(*(const bf16x8*)&kr[0],  *(const bf16x8*)&qs[l15][quad * 8],      lg);
      lg = MFMA16(*(const bf16x8*)&kr[32], *(const bf16x8*)&qs[l15][32 + quad * 8], lg);
      #pragma unroll
      for (int r = 0; r < 4; ++r) {
        const float l = lg[r];
        float m = l;
        m = fmaxf(m, __shfl_xor(m, 1));
        m = fmaxf(m, __shfl_xor(m, 2));
        m = fmaxf(m, __shfl_xor(m, 4));
        const float e = expf(l - m);
        float ss = e;
        ss += __shfl_xor(ss, 1);
        ss += __shfl_xor(ss, 2);
        ss += __shfl_xor(ss, 4);
        const float at = e / ss + 1e-8f;
        if (l15 < 8) {
          const bf16 ab = (bf16)at;
          attn_b[l15][t0 + quad * 4 + r] = ab;
          cs += (float)ab;
        }
      }
    }
    cs += __shfl_xor(cs, 16);
    cs += __shfl_xor(cs, 32);
    if (lane < 8) cspart[wvid][lane] = cs;
  }
  __syncthreads();

  // PV: per wave K=32 tokens; A = attn (A-frag-ready), B = vT rows from global
  {
    const bf16x8 afr = *(const bf16x8*)&attn_b[l15][wvid * 32 + quad * 8];
    const bf16* vrow = vT + (size_t)b * 131072 + (size_t)ch * 128 + wvid * 32 + quad * 8;
    const f32x4 zero4 = {0.f, 0.f, 0.f, 0.f};
    #pragma unroll
    for (int nt = 0; nt < 4; ++nt) {
      const bf16x8 bv = *(const bf16x8*)&vrow[(size_t)(nt * 16 + l15) * 2048];
      f32x4 dd = MFMA16(afr, bv, zero4);
      if (quad < 2) {
        #pragma unroll
        for (int r = 0; r < 4; ++r)
          updp[wvid][quad * 4 + r][nt * 16 + l15] = dd[r];
      }
    }
  }
  __syncthreads();

  {
    const float* up = &updp[0][0][0];
    float* og = updpart + ((size_t)b * 16 + ch) * 512;
    for (int o = tid; o < 512; o += 256)
      og[o] = up[o] + up[o + 512] + up[o + 1024] + up[o + 1536];
    if (tid < 8)
      colpart[((size_t)b * 16 + ch) * 8 + tid] =
        cspart[0][tid] + cspart[1][tid] + cspart[2][tid] + cspart[3][tid];
  }
}

// ---------------- kB: reduce + GRU + MLP + next-q / head ----------------
// grid 128, block 1024 (16 waves): halved serial j-loops + 4 waves/SIMD.
__global__ __launch_bounds__(1024) void kB(
    const float* __restrict__ updpart, const float* __restrict__ colpart,
    float* __restrict__ slotbuf, bf16* __restrict__ qbuf,
    const float* __restrict__ nsw, const float* __restrict__ nsb,
    const float* __restrict__ nmw, const float* __restrict__ nmb,
    const float* __restrict__ Wq,
    const float* __restrict__ wih, const float* __restrict__ whh,
    const float* __restrict__ bih, const float* __restrict__ bhh,
    const float* __restrict__ w1,  const float* __restrict__ b1,
    const float* __restrict__ w2,  const float* __restrict__ b2,
    const float* __restrict__ hwt, const float* __restrict__ hb,
    float* __restrict__ out, const int last)
{
  __shared__ float slots[8][66];
  __shared__ float tmp[8][66];
  __shared__ float gig[8][192], ghg[8][192];
  __shared__ float h1[8][132];
  const int b = blockIdx.x, tid = threadIdx.x;
  const int s0 = (tid >> 6) & 7, d0 = tid & 63;    // valid when tid<512
  const int part = tid & 7, sl = (tid >> 3) & 7;
  const int wv16 = tid >> 6;                       // wave id 0..15

  if (tid < 512) {
    const float* up = updpart + (size_t)b * 8192 + s0 * 64 + d0;
    float u = 0.f;
    #pragma unroll
    for (int ch = 0; ch < 16; ++ch) u += up[ch * 512];
    const float* cp = colpart + (size_t)b * 128 + s0;
    float cs = 0.f;
    #pragma unroll
    for (int ch = 0; ch < 16; ++ch) cs += cp[ch * 8];
    tmp[s0][d0] = u / cs;
    slots[s0][d0] = slotbuf[((size_t)b * 8 + s0) * 64 + d0];
  }
  __syncthreads();

  // GRU gates: 16 waves, j = jr*16 + wv16, jr < 12
  {
    float tv[8], sv[8];
    #pragma unroll
    for (int i = 0; i < 8; ++i) { tv[i] = tmp[sl][part * 8 + i]; sv[i] = slots[sl][part * 8 + i]; }
    for (int jr = 0; jr < 12; ++jr) {
      const int j = jr * 16 + wv16;
      const f32x4 wa0 = *(const f32x4*)&wih[j * 64 + part * 8];
      const f32x4 wa1 = *(const f32x4*)&wih[j * 64 + part * 8 + 4];
      const f32x4 wb0 = *(const f32x4*)&whh[j * 64 + part * 8];
      const f32x4 wb1 = *(const f32x4*)&whh[j * 64 + part * 8 + 4];
      float a = tv[0]*wa0[0] + tv[1]*wa0[1] + tv[2]*wa0[2] + tv[3]*wa0[3]
              + tv[4]*wa1[0] + tv[5]*wa1[1] + tv[6]*wa1[2] + tv[7]*wa1[3];
      float h = sv[0]*wb0[0] + sv[1]*wb0[1] + sv[2]*wb0[2] + sv[3]*wb0[3]
              + sv[4]*wb1[0] + sv[5]*wb1[1] + sv[6]*wb1[2] + sv[7]*wb1[3];
      a += __shfl_xor(a, 1); a += __shfl_xor(a, 2); a += __shfl_xor(a, 4);
      h += __shfl_xor(h, 1); h += __shfl_xor(h, 2); h += __shfl_xor(h, 4);
      if (part == 0) { gig[sl][j] = a + bih[j]; ghg[sl][j] = h + bhh[j]; }
    }
  }
  __syncthreads();

  if (tid < 512) {
    const float r  = 1.f / (1.f + expf(-(gig[s0][d0]       + ghg[s0][d0])));
    const float z  = 1.f / (1.f + expf(-(gig[s0][64 + d0]  + ghg[s0][64 + d0])));
    const float nn = tanhf(gig[s0][128 + d0] + r * ghg[s0][128 + d0]);
    const float snew = (1.f - z) * nn + z * slots[s0][d0];
    slots[s0][d0] = snew;
    float s = snew, s2 = snew * snew;
    #pragma unroll
    for (int m = 1; m < 64; m <<= 1) { s += __shfl_xor(s, m); s2 += __shfl_xor(s2, m); }
    const float mu = s * 0.015625f;
    const float rstd = rsqrtf(s2 * 0.015625f - mu * mu + 1e-5f);
    tmp[s0][d0] = (snew - mu) * rstd * nmw[d0] + nmb[d0];
  }
  __syncthreads();

  // MLP hidden: j = jr*16 + wv16, jr < 8
  {
    float tm[8];
    #pragma unroll
    for (int i = 0; i < 8; ++i) tm[i] = tmp[sl][part * 8 + i];
    for (int jr = 0; jr < 8; ++jr) {
      const int j = jr * 16 + wv16;
      const f32x4 w0 = *(const f32x4*)&w1[j * 64 + part * 8];
      const f32x4 w1v = *(const f32x4*)&w1[j * 64 + part * 8 + 4];
      float a = tm[0]*w0[0] + tm[1]*w0[1] + tm[2]*w0[2] + tm[3]*w0[3]
              + tm[4]*w1v[0] + tm[5]*w1v[1] + tm[6]*w1v[2] + tm[7]*w1v[3];
      a += __shfl_xor(a, 1); a += __shfl_xor(a, 2); a += __shfl_xor(a, 4);
      if (part == 0) h1[sl][j] = fmaxf(a + b1[j], 0.f);
    }
  }
  __syncthreads();

  // MLP out + residual: d = orr*16 + wv16, orr < 4
  for (int orr = 0; orr < 4; ++orr) {
    const int d = orr * 16 + wv16;
    float a = 0.f;
    #pragma unroll
    for (int i = 0; i < 4; ++i) {
      const f32x4 wv4 = *(const f32x4*)&w2[d * 128 + part * 16 + i * 4];
      a += h1[sl][part * 16 + i * 4 + 0] * wv4[0] + h1[sl][part * 16 + i * 4 + 1] * wv4[1]
         + h1[sl][part * 16 + i * 4 + 2] * wv4[2] + h1[sl][part * 16 + i * 4 + 3] * wv4[3];
    }
    a += __shfl_xor(a, 1); a += __shfl_xor(a, 2); a += __shfl_xor(a, 4);
    if (part == 0) slots[sl][d] += a + b2[d];
  }
  __syncthreads();

  if (!last) {
    if (tid < 512) {
      const float sfin = slots[s0][d0];
      slotbuf[((size_t)b * 8 + s0) * 64 + d0] = sfin;
      float s = sfin, s2 = sfin * sfin;
      #pragma unroll
      for (int m = 1; m < 64; m <<= 1) { s += __shfl_xor(s, m); s2 += __shfl_xor(s2, m); }
      const float mu = s * 0.015625f;
      const float rstd = rsqrtf(s2 * 0.015625f - mu * mu + 1e-5f);
      tmp[s0][d0] = (sfin - mu) * rstd * nsw[d0] + nsb[d0];
    }
    __syncthreads();
    float tm[8];
    #pragma unroll
    for (int i = 0; i < 8; ++i) tm[i] = tmp[sl][part * 8 + i];
    for (int orr = 0; orr < 4; ++orr) {
      const int d = orr * 16 + wv16;
      const f32x4 w0 = *(const f32x4*)&Wq[d * 64 + part * 8];
      const f32x4 w1v = *(const f32x4*)&Wq[d * 64 + part * 8 + 4];
      float a = tm[0]*w0[0] + tm[1]*w0[1] + tm[2]*w0[2] + tm[3]*w0[3]
              + tm[4]*w1v[0] + tm[5]*w1v[1] + tm[6]*w1v[2] + tm[7]*w1v[3];
      a += __shfl_xor(a, 1); a += __shfl_xor(a, 2); a += __shfl_xor(a, 4);
      if (part == 0) qbuf[((size_t)b * 8 + sl) * 64 + d] = (bf16)(a * 0.125f);
    }
  } else {
    if (tid < 512) slotbuf[((size_t)b * 8 + s0) * 64 + d0] = slots[s0][d0];
    if (tid < 64) {
      float f = 0.f;
      #pragma unroll
      for (int s = 0; s < 8; ++s) f += slots[s][tid];
      tmp[0][tid] = f * 0.125f;
    }
    __syncthreads();
    if (tid < 15) {
      float a = hb[tid];
      for (int d = 0; d < 64; ++d) a += tmp[0][d] * hwt[tid * 64 + d];
      out[b * 15 + tid] = a;
    }
  }
}

extern "C" void kernel_launch(void* const* d_in, const int* in_sizes, int n_in,
                              void* d_out, int out_size, void* d_ws, size_t ws_size,
                              hipStream_t stream) {
  const float* x1   = (const float*)d_in[0];
  const float* x2   = (const float*)d_in[1];
  const float* c1w  = (const float*)d_in[2];
  const float* c1b  = (const float*)d_in[3];
  const float* c2w  = (const float*)d_in[4];
  const float* c2b  = (const float*)d_in[5];
  const float* nw   = (const float*)d_in[6];
  const float* nb   = (const float*)d_in[7];
  const float* niw  = (const float*)d_in[8];
  const float* nib  = (const float*)d_in[9];
  const float* nsw  = (const float*)d_in[10];
  const float* nsb  = (const float*)d_in[11];
  const float* nmw  = (const float*)d_in[12];
  const float* nmb  = (const float*)d_in[13];
  const float* smu  = (const float*)d_in[14];
  const float* slog = (const float*)d_in[15];
  const float* Wq   = (const float*)d_in[16];
  const float* Wk   = (const float*)d_in[17];
  const float* Wv   = (const float*)d_in[18];
  const float* wih  = (const float*)d_in[19];
  const float* whh  = (const float*)d_in[20];
  const float* bih  = (const float*)d_in[21];
  const float* bhh  = (const float*)d_in[22];
  const float* w1   = (const float*)d_in[23];
  const float* b1   = (const float*)d_in[24];
  const float* w2   = (const float*)d_in[25];
  const float* b2   = (const float*)d_in[26];
  const float* hwt  = (const float*)d_in[27];
  const float* hb   = (const float*)d_in[28];
  const float* noise= (const float*)d_in[29];

  char* ws = (char*)d_ws;
  bf16*  kbuf    = (bf16*)(ws);
  bf16*  vT      = (bf16*)(ws + (size_t)33554432);
  bf16*  wconv   = (bf16*)(ws + (size_t)67108864);
  bf16*  wkv     = (bf16*)(ws + (size_t)67174400);
  float* slotbuf = (float*)(ws + (size_t)67190784);
  bf16*  qbuf    = (bf16*)(ws + (size_t)67452928);
  float* updpart = (float*)(ws + (size_t)67584000);
  float* colpart = (float*)(ws + (size_t)71778304);

  k0_convert<<<dim3(64), dim3(256), 0, stream>>>(c1w, c2w, Wk, Wv, wconv, wkv);
  k1_conv_kv<<<dim3(4096), dim3(256), 0, stream>>>(x1, x2, c1b, c2b, nw, nb, niw, nib,
                                                   wconv, wkv, kbuf, vT);
  kS0<<<dim3(128), dim3(512), 0, stream>>>(smu, slog, noise, nsw, nsb, Wq, slotbuf, qbuf);
  for (int it = 0; it < 3; ++it) {
    kA<<<dim3(2048), dim3(256), 0, stream>>>(kbuf, vT, qbuf, updpart, colpart);
    kB<<<dim3(128), dim3(1024), 0, stream>>>(updpart, colpart, slotbuf, qbuf,
                                             nsw, nsb, nmw, nmb, Wq,
                                             wih, whh, bih, bhh, w1, b1, w2, b2,
                                             hwt, hb, (float*)d_out, (it == 2) ? 1 : 0);
  }
}